// Round 2
// baseline (934.234 us; speedup 1.0000x reference)
//
#include <hip/hip_runtime.h>
#include <math.h>

// Problem constants
#define NB 2048   // batch
#define NIN 512   // input width
#define NK 16     // K (patch/channel width)
#define NH 8      // H hidden per direction
#define NL 497    // L = IN - K + 1
#define NT 96     // decode steps
#define NREP 32   // BN accumulator replicas (atomic contention fix)

// ---------- math helpers ----------
__device__ __forceinline__ float gelu_exact(float x) {
    return 0.5f * x * (1.0f + erff(x * 0.70710678118654752440f));
}

// sigmoid for gates i,f,o ; tanh for gate g — branchless via select.
__device__ __forceinline__ float gate_act(float acc, bool isG) {
    float mm = isG ? 2.0f : 1.0f;
    float e  = __expf(-mm * acc);
    float s  = 1.0f / (1.0f + e);
    return isG ? 2.0f * s - 1.0f : s;
}

// inf-safe tanh (cell state can be any sign/magnitude)
__device__ __forceinline__ float tanh_safe(float x) {
    float t = __expf(-2.0f * fabsf(x));
    float r = 1.0f - 2.0f * t / (1.0f + t);
    return copysignf(r, x);
}

__device__ __forceinline__ void load16(const float* __restrict__ ptr, float* dst) {
    const float4* rp = (const float4*)ptr;
    float4 a = rp[0], b = rp[1], c = rp[2], d = rp[3];
    dst[0]=a.x; dst[1]=a.y; dst[2]=a.z;  dst[3]=a.w;
    dst[4]=b.x; dst[5]=b.y; dst[6]=b.z;  dst[7]=b.w;
    dst[8]=c.x; dst[9]=c.y; dst[10]=c.z; dst[11]=c.w;
    dst[12]=d.x;dst[13]=d.y;dst[14]=d.z; dst[15]=d.w;
}

// ---------- K1: patch + seg matmul + gelu + BN partial sums ----------
// p[b,l,k] = gelu( sum_k' (x[b,l+k'] + pe[l,k']) * Wseg[k,k'] + bseg[k] )
// bn[rep][l] += sum_k p ; bn[rep][512+l] += sum_k p^2  (rep = blockIdx & 31)
__global__ __launch_bounds__(256) void k_seg(
    const float* __restrict__ x, const float* __restrict__ pe,
    const float* __restrict__ Wseg, const float* __restrict__ bseg,
    float* __restrict__ p, float* __restrict__ bn)
{
    __shared__ float xs[NIN];
    __shared__ float ws[NK * NK];
    __shared__ float bs[NK];
    const int tid = threadIdx.x;
    const int b = blockIdx.x;
    float* bnr = bn + (size_t)(b & (NREP - 1)) * 1024;
    for (int i = tid; i < NIN; i += 256) xs[i] = x[(size_t)b * NIN + i];
    if (tid < NK * NK) ws[tid] = Wseg[tid];
    if (tid < NK) bs[tid] = bseg[tid];
    __syncthreads();

    for (int l = tid; l < NL; l += 256) {
        float u[NK];
        load16(pe + l * NK, u);
        #pragma unroll
        for (int k = 0; k < NK; k++) u[k] += xs[l + k];
        float out[NK];
        float s = 0.f, s2 = 0.f;
        #pragma unroll
        for (int k = 0; k < NK; k++) {
            float acc = bs[k];
            #pragma unroll
            for (int kp = 0; kp < NK; kp++) acc += u[kp] * ws[k * NK + kp];
            float gv = gelu_exact(acc);
            out[k] = gv; s += gv; s2 += gv * gv;
        }
        float4* pr = (float4*)(p + ((size_t)b * NL + l) * NK);
        pr[0] = make_float4(out[0], out[1], out[2], out[3]);
        pr[1] = make_float4(out[4], out[5], out[6], out[7]);
        pr[2] = make_float4(out[8], out[9], out[10], out[11]);
        pr[3] = make_float4(out[12], out[13], out[14], out[15]);
        atomicAdd(&bnr[l], s);
        atomicAdd(&bnr[512 + l], s2);
    }
}

// ---------- K2: finalize BN -> per-position scale/shift ----------
// ansh[l] = g_bn[l]*rsqrt(var+eps), ansh[512+l] = b_bn[l] - mu*ansh[l]
__global__ void k_bnfin(const float* __restrict__ bn, const float* __restrict__ gbn,
                        const float* __restrict__ bbn, float* __restrict__ ansh)
{
    int l = blockIdx.x * blockDim.x + threadIdx.x;
    if (l < NL) {
        float s = 0.f, s2 = 0.f;
        #pragma unroll 4
        for (int r = 0; r < NREP; r++) {
            s  += bn[(size_t)r * 1024 + l];
            s2 += bn[(size_t)r * 1024 + 512 + l];
        }
        const float inv = 1.0f / (float)(NB * NK);
        float mu  = s * inv;
        float var = s2 * inv - mu * mu;
        float rr  = rsqrtf(var + 1e-5f);
        float av  = gbn[l] * rr;
        ansh[l] = av;
        ansh[512 + l] = bbn[l] - mu * av;
    }
}

// ---------- K3: bidirectional LSTM sweep over L ----------
// One wave per batch element. lanes 0-31: forward cell, 32-63: backward cell.
// lane = 32*d + g, gate order [i(0-7) f(8-15) g(16-23) o(24-31)], j = g&7.
// NORM: input rows are raw p; apply xe = a[t]*p + sh[t] via dot trick.
// WRITE_O: store h into oout[b,t, d*8+j]. WRITE_LAST: backward first step -> oblast.
// st layout: [hF | cF | hB | cB], each NB*8.
template<int NORM, int WRITE_O, int WRITE_LAST>
__global__ __launch_bounds__(256) void k_lstm(
    const float* __restrict__ src, const float* __restrict__ ansh,
    const float* __restrict__ WihF, const float* __restrict__ WhhF,
    const float* __restrict__ WihB, const float* __restrict__ WhhB,
    float* __restrict__ oout, float* __restrict__ st, float* __restrict__ oblast)
{
    const int tid = threadIdx.x;
    const int lane = tid & 63;
    const int b = blockIdx.x * 4 + (tid >> 6);
    const int d = lane >> 5, g = lane & 31, j = g & 7;
    const int base = d << 5;
    const float* Wih = d ? WihB : WihF;
    const float* Whh = d ? WhhB : WhhF;
    float wih[16], whh[8];
    #pragma unroll
    for (int k = 0; k < 16; k++) wih[k] = Wih[g * 16 + k];
    #pragma unroll
    for (int k = 0; k < 8; k++)  whh[k] = Whh[g * 8 + k];
    float Sg = 0.f;
    if constexpr (NORM) {
        #pragma unroll
        for (int k = 0; k < 16; k++) Sg += wih[k];
    }
    float h = 0.f, c = 0.f;
    const float* srcb = src + (size_t)b * NL * NK;
    const bool isG = (g >= 16) && (g < 24);

    // software pipeline: xr holds row for step s; xn prefetches s+1
    float xr[16];
    load16(srcb + (d ? (NL - 1) : 0) * NK, xr);

    for (int s = 0; s < NL; s++) {
        const int t = d ? (NL - 1 - s) : s;
        // input dot for current step (xr already resident)
        float acc = 0.f;
        #pragma unroll
        for (int k = 0; k < 16; k++) acc += xr[k] * wih[k];
        if constexpr (NORM) {
            float at = ansh[t], sht = ansh[512 + t];
            acc = at * acc + sht * Sg;
        }
        // prefetch next row — VMEM latency hides under shfl+exp chain below
        float xn[16];
        if (s + 1 < NL) {
            const int tn = d ? (NL - 2 - s) : (s + 1);
            load16(srcb + tn * NK, xn);
        }
        #pragma unroll
        for (int k = 0; k < 8; k++) {
            float hk = __shfl(h, base + k, 64);
            acc += whh[k] * hk;
        }
        float val = gate_act(acc, isG);
        float fv = __shfl(val, lane + 8, 64);
        float gv = __shfl(val, lane + 16, 64);
        float ov = __shfl(val, lane + 24, 64);
        float cn = fv * c + val * gv;      // valid for g<8 (val = sigmoid(i))
        float hn = ov * tanh_safe(cn);
        if (g < 8) { c = cn; h = hn; }
        if constexpr (WRITE_O) {
            if (g < 8) oout[((size_t)b * NL + t) * NK + (d << 3) + j] = hn;
        }
        if constexpr (WRITE_LAST) {
            if (s == 0 && d == 1 && g < 8) oblast[b * 8 + j] = hn;
        }
        #pragma unroll
        for (int k = 0; k < 16; k++) xr[k] = xn[k];
    }
    if (g < 8) {
        float* hs = st + (d ? (size_t)2 * NB * 8 : 0);
        hs[b * 8 + j] = h;
        hs[(size_t)NB * 8 + b * 8 + j] = c;
    }
}

// ---------- K4: 96-step decode recurrence (cells only), store raw o to z ----------
__global__ __launch_bounds__(256) void k_dec(
    const float* __restrict__ Wf0, const float* __restrict__ Uf0,
    const float* __restrict__ Wb0, const float* __restrict__ Ub0,
    const float* __restrict__ Wf1, const float* __restrict__ Uf1,
    const float* __restrict__ Wb1, const float* __restrict__ Ub1,
    const float* __restrict__ st0, const float* __restrict__ st1,
    const float* __restrict__ oblast, const float* __restrict__ p,
    const float* __restrict__ ansh,
    const float* __restrict__ gln, const float* __restrict__ bln,
    float* __restrict__ z)
{
    const int tid = threadIdx.x, lane = tid & 63;
    const int b = blockIdx.x * 4 + (tid >> 6);
    const int d = lane >> 5, g = lane & 31, j = g & 7, base = d << 5;
    const float* Wih0 = d ? Wb0 : Wf0; const float* Whh0 = d ? Ub0 : Uf0;
    const float* Wih1 = d ? Wb1 : Wf1; const float* Whh1 = d ? Ub1 : Uf1;
    float wih0[16], whh0[8], wih1[16], whh1[8];
    #pragma unroll
    for (int k = 0; k < 16; k++) { wih0[k] = Wih0[g * 16 + k]; wih1[k] = Wih1[g * 16 + k]; }
    #pragma unroll
    for (int k = 0; k < 8; k++)  { whh0[k] = Whh0[g * 8 + k]; whh1[k] = Whh1[g * 8 + k]; }

    float h0 = 0.f, c0 = 0.f, h1 = 0.f, c1 = 0.f;
    if (g < 8) {
        const float* s0 = st0 + (d ? (size_t)2 * NB * 8 : 0);
        h0 = s0[b * 8 + j]; c0 = s0[(size_t)NB * 8 + b * 8 + j];
        const float* s1 = st1 + (d ? (size_t)2 * NB * 8 : 0);
        h1 = s1[b * 8 + j]; c1 = s1[(size_t)NB * 8 + b * 8 + j];
    }

    // fb = LN(concat(hf1_final, ob1_last)) * g_ln + b_ln + xe[:,L-1,:]
    float fb[16];
    {
        float ol[16];
        #pragma unroll
        for (int k = 0; k < 8; k++) ol[k] = st1[b * 8 + k];          // hF1 final == of1[:,L-1]
        #pragma unroll
        for (int k = 0; k < 8; k++) ol[8 + k] = oblast[b * 8 + k];   // ob1[:,L-1]
        float mn = 0.f;
        #pragma unroll
        for (int k = 0; k < 16; k++) mn += ol[k];
        mn *= (1.0f / 16.0f);
        float vv = 0.f;
        #pragma unroll
        for (int k = 0; k < 16; k++) { float dq = ol[k] - mn; vv += dq * dq; }
        vv *= (1.0f / 16.0f);
        float rr = rsqrtf(vv + 1e-5f);
        float aL = ansh[NL - 1], sL = ansh[512 + NL - 1];
        const float* prow = p + ((size_t)b * NL + (NL - 1)) * NK;
        #pragma unroll
        for (int k = 0; k < 16; k++)
            fb[k] = (ol[k] - mn) * rr * gln[k] + bln[k] + (prow[k] * aL + sL);
    }

    const bool isG = (g >= 16) && (g < 24);
    for (int t = 0; t < NT; t++) {
        // layer-0 cell
        float acc = 0.f;
        #pragma unroll
        for (int k = 0; k < 16; k++) acc += fb[k] * wih0[k];
        #pragma unroll
        for (int k = 0; k < 8; k++) acc += whh0[k] * __shfl(h0, base + k, 64);
        float val = gate_act(acc, isG);
        float fv = __shfl(val, lane + 8, 64);
        float gv = __shfl(val, lane + 16, 64);
        float ov = __shfl(val, lane + 24, 64);
        float cn = fv * c0 + val * gv;
        float hn = ov * tanh_safe(cn);
        if (g < 8) { c0 = cn; h0 = hn; }
        // m0 = concat(hf0, hb0) broadcast to all lanes
        float m0[16];
        #pragma unroll
        for (int k = 0; k < 16; k++) m0[k] = __shfl(h0, k < 8 ? k : 24 + k, 64);
        // layer-1 cell
        acc = 0.f;
        #pragma unroll
        for (int k = 0; k < 16; k++) acc += m0[k] * wih1[k];
        #pragma unroll
        for (int k = 0; k < 8; k++) acc += whh1[k] * __shfl(h1, base + k, 64);
        val = gate_act(acc, isG);
        fv = __shfl(val, lane + 8, 64);
        gv = __shfl(val, lane + 16, 64);
        ov = __shfl(val, lane + 24, 64);
        cn = fv * c1 + val * gv;
        hn = ov * tanh_safe(cn);
        if (g < 8) { c1 = cn; h1 = hn; }
        if (g < 8) z[((size_t)b * NT + t) * NK + (d << 3) + j] = hn;
        // new fb = raw o = concat(hf1, hb1)
        #pragma unroll
        for (int k = 0; k < 16; k++) fb[k] = __shfl(h1, k < 8 ? k : 24 + k, 64);
    }
}

// ---------- K5: decoder MLP over all (b,t) rows: y = gelu(LN(z)@W1^T + b1)@W2^T + b2 ----------
__global__ __launch_bounds__(256) void k_head(
    const float* __restrict__ z, const float* __restrict__ gln, const float* __restrict__ bln,
    const float* __restrict__ W1, const float* __restrict__ b1,
    const float* __restrict__ W2, const float* __restrict__ b2,
    float* __restrict__ outp)
{
    __shared__ float w1s[512 * 16];
    __shared__ float b1s[512];
    __shared__ float w2s[512];
    const int tid = threadIdx.x;
    for (int i = tid; i < 512 * 16 / 4; i += 256)
        ((float4*)w1s)[i] = ((const float4*)W1)[i];
    for (int i = tid; i < 512; i += 256) { b1s[i] = b1[i]; w2s[i] = W2[i]; }
    __syncthreads();

    const size_t r = (size_t)blockIdx.x * 256 + tid;   // r = b*NT + t, matches out layout
    float zr[16];
    load16(z + r * 16, zr);
    float mn = 0.f;
    #pragma unroll
    for (int k = 0; k < 16; k++) mn += zr[k];
    mn *= (1.0f / 16.0f);
    float vv = 0.f;
    #pragma unroll
    for (int k = 0; k < 16; k++) { float dq = zr[k] - mn; vv += dq * dq; }
    vv *= (1.0f / 16.0f);
    float rr = rsqrtf(vv + 1e-5f);
    float zn[16];
    #pragma unroll
    for (int k = 0; k < 16; k++) zn[k] = (zr[k] - mn) * rr * gln[k] + bln[k];

    float y = b2[0];
    #pragma unroll 2
    for (int i = 0; i < 512; i++) {
        float acc = b1s[i];
        #pragma unroll
        for (int k = 0; k < 16; k++) acc += zn[k] * w1s[i * 16 + k];
        y += gelu_exact(acc) * w2s[i];
    }
    outp[r] = y;
}

// ---------- launcher ----------
extern "C" void kernel_launch(void* const* d_in, const int* in_sizes, int n_in,
                              void* d_out, int out_size, void* d_ws, size_t ws_size,
                              hipStream_t stream)
{
    const float* x    = (const float*)d_in[0];
    const float* pe   = (const float*)d_in[1];
    const float* Wseg = (const float*)d_in[2];
    const float* bseg = (const float*)d_in[3];
    const float* gbn  = (const float*)d_in[4];
    const float* bbn  = (const float*)d_in[5];
    const float* Wf0  = (const float*)d_in[6];
    const float* Uf0  = (const float*)d_in[7];
    const float* Wb0  = (const float*)d_in[8];
    const float* Ub0  = (const float*)d_in[9];
    const float* Wf1  = (const float*)d_in[10];
    const float* Uf1  = (const float*)d_in[11];
    const float* Wb1  = (const float*)d_in[12];
    const float* Ub1  = (const float*)d_in[13];
    const float* gln  = (const float*)d_in[14];
    const float* bln  = (const float*)d_in[15];
    const float* W1   = (const float*)d_in[16];
    const float* b1   = (const float*)d_in[17];
    const float* W2   = (const float*)d_in[18];
    const float* b2   = (const float*)d_in[19];

    char* ws = (char*)d_ws;
    size_t off = 0;
    auto take = [&](size_t bytes) -> char* {
        char* r = ws + off;
        off = (off + bytes + 255) & ~(size_t)255;
        return r;
    };
    float* p    = (float*)take((size_t)NB * NL * NK * 4);   // 65.1 MB
    float* o0   = (float*)take((size_t)NB * NL * NK * 4);   // 65.1 MB
    float* z    = (float*)take((size_t)NB * NT * NK * 4);   // 12.6 MB
    float* bn   = (float*)take((size_t)NREP * 1024 * 4);    // 32 replicas of sums|sumsq
    float* ansh = (float*)take(1024 * 4);                   // a[512] | sh[512]
    float* st0  = (float*)take((size_t)4 * NB * 8 * 4);     // hF|cF|hB|cB layer0
    float* st1  = (float*)take((size_t)4 * NB * 8 * 4);     // layer1
    float* obl  = (float*)take((size_t)NB * 8 * 4);         // ob1[:,L-1]

    hipMemsetAsync(bn, 0, (size_t)NREP * 1024 * 4, stream);
    k_seg<<<NB, 256, 0, stream>>>(x, pe, Wseg, bseg, p, bn);
    k_bnfin<<<2, 256, 0, stream>>>(bn, gbn, bbn, ansh);
    k_lstm<1, 1, 0><<<NB / 4, 256, 0, stream>>>(p, ansh, Wf0, Uf0, Wb0, Ub0, o0, st0, nullptr);
    k_lstm<0, 0, 1><<<NB / 4, 256, 0, stream>>>(o0, nullptr, Wf1, Uf1, Wb1, Ub1, nullptr, st1, obl);
    k_dec<<<NB / 4, 256, 0, stream>>>(Wf0, Uf0, Wb0, Ub0, Wf1, Uf1, Wb1, Ub1,
                                      st0, st1, obl, p, ansh, gln, bln, z);
    k_head<<<(NB * NT) / 256, 256, 0, stream>>>(z, gln, bln, W1, b1, W2, b2, (float*)d_out);
}

// Round 3
// 728.086 us; speedup vs baseline: 1.2831x; 1.2831x over previous
//
#include <hip/hip_runtime.h>
#include <math.h>

// Problem constants
#define NB 2048   // batch
#define NIN 512   // input width
#define NK 16     // K (patch/channel width)
#define NH 8      // H hidden per direction
#define NL 497    // L = IN - K + 1
#define NT 96     // decode steps
#define NREP 32   // BN accumulator replicas (atomic contention fix)

// ---------- math helpers ----------
__device__ __forceinline__ float gelu_exact(float x) {
    return 0.5f * x * (1.0f + erff(x * 0.70710678118654752440f));
}

// sigmoid for gates i,f,o ; tanh for gate g — branchless via select.
__device__ __forceinline__ float gate_act(float acc, bool isG) {
    float mm = isG ? 2.0f : 1.0f;
    float e  = __expf(-mm * acc);
    float s  = 1.0f / (1.0f + e);
    return isG ? 2.0f * s - 1.0f : s;
}

// inf-safe tanh (cell state can be any sign/magnitude)
__device__ __forceinline__ float tanh_safe(float x) {
    float t = __expf(-2.0f * fabsf(x));
    float r = 1.0f - 2.0f * t / (1.0f + t);
    return copysignf(r, x);
}

__device__ __forceinline__ void load16(const float* __restrict__ ptr, float* dst) {
    const float4* rp = (const float4*)ptr;
    float4 a = rp[0], b = rp[1], c = rp[2], d = rp[3];
    dst[0]=a.x; dst[1]=a.y; dst[2]=a.z;  dst[3]=a.w;
    dst[4]=b.x; dst[5]=b.y; dst[6]=b.z;  dst[7]=b.w;
    dst[8]=c.x; dst[9]=c.y; dst[10]=c.z; dst[11]=c.w;
    dst[12]=d.x;dst[13]=d.y;dst[14]=d.z; dst[15]=d.w;
}

// ---------- K1: patch + seg matmul + gelu + BN partial sums ----------
__global__ __launch_bounds__(256) void k_seg(
    const float* __restrict__ x, const float* __restrict__ pe,
    const float* __restrict__ Wseg, const float* __restrict__ bseg,
    float* __restrict__ p, float* __restrict__ bn)
{
    __shared__ float xs[NIN];
    __shared__ float ws[NK * NK];
    __shared__ float bs[NK];
    const int tid = threadIdx.x;
    const int b = blockIdx.x;
    float* bnr = bn + (size_t)(b & (NREP - 1)) * 1024;
    for (int i = tid; i < NIN; i += 256) xs[i] = x[(size_t)b * NIN + i];
    if (tid < NK * NK) ws[tid] = Wseg[tid];
    if (tid < NK) bs[tid] = bseg[tid];
    __syncthreads();

    for (int l = tid; l < NL; l += 256) {
        float u[NK];
        load16(pe + l * NK, u);
        #pragma unroll
        for (int k = 0; k < NK; k++) u[k] += xs[l + k];
        float out[NK];
        float s = 0.f, s2 = 0.f;
        #pragma unroll
        for (int k = 0; k < NK; k++) {
            float acc = bs[k];
            #pragma unroll
            for (int kp = 0; kp < NK; kp++) acc += u[kp] * ws[k * NK + kp];
            float gv = gelu_exact(acc);
            out[k] = gv; s += gv; s2 += gv * gv;
        }
        float4* pr = (float4*)(p + ((size_t)b * NL + l) * NK);
        pr[0] = make_float4(out[0], out[1], out[2], out[3]);
        pr[1] = make_float4(out[4], out[5], out[6], out[7]);
        pr[2] = make_float4(out[8], out[9], out[10], out[11]);
        pr[3] = make_float4(out[12], out[13], out[14], out[15]);
        atomicAdd(&bnr[l], s);
        atomicAdd(&bnr[512 + l], s2);
    }
}

// ---------- K2: finalize BN -> interleaved per-position (a, sh) pairs ----------
// ansh[2l] = g_bn[l]*rsqrt(var+eps), ansh[2l+1] = b_bn[l] - mu*ansh[2l]
__global__ void k_bnfin(const float* __restrict__ bn, const float* __restrict__ gbn,
                        const float* __restrict__ bbn, float* __restrict__ ansh)
{
    int l = blockIdx.x * blockDim.x + threadIdx.x;
    if (l < NL) {
        float s = 0.f, s2 = 0.f;
        #pragma unroll 4
        for (int r = 0; r < NREP; r++) {
            s  += bn[(size_t)r * 1024 + l];
            s2 += bn[(size_t)r * 1024 + 512 + l];
        }
        const float inv = 1.0f / (float)(NB * NK);
        float mu  = s * inv;
        float var = s2 * inv - mu * mu;
        float rr  = rsqrtf(var + 1e-5f);
        float av  = gbn[l] * rr;
        ansh[2 * l]     = av;
        ansh[2 * l + 1] = bbn[l] - mu * av;
    }
}

// ---------- K3: bidirectional LSTM sweep over L, 4-deep register pipeline ----------
// One wave per batch element. lanes 0-31: forward cell, 32-63: backward cell.
// lane = 32*d + g, gate order [i(0-7) f(8-15) g(16-23) o(24-31)], j = g&7.
template<int NORM, int WRITE_O, int WRITE_LAST>
__global__ __launch_bounds__(256) void k_lstm(
    const float* __restrict__ src, const float* __restrict__ ansh,
    const float* __restrict__ WihF, const float* __restrict__ WhhF,
    const float* __restrict__ WihB, const float* __restrict__ WhhB,
    float* __restrict__ oout, float* __restrict__ st, float* __restrict__ oblast)
{
    const int tid = threadIdx.x;
    const int lane = tid & 63;
    const int b = blockIdx.x * 4 + (tid >> 6);
    const int d = lane >> 5, g = lane & 31, j = g & 7;
    const int base = d << 5;
    const float* Wih = d ? WihB : WihF;
    const float* Whh = d ? WhhB : WhhF;
    float wih[16], whh[8];
    #pragma unroll
    for (int k = 0; k < 16; k++) wih[k] = Wih[g * 16 + k];
    #pragma unroll
    for (int k = 0; k < 8; k++)  whh[k] = Whh[g * 8 + k];
    float Sg = 0.f;
    if constexpr (NORM) {
        #pragma unroll
        for (int k = 0; k < 16; k++) Sg += wih[k];
    }
    float h = 0.f, c = 0.f;
    const float* srcb = src + (size_t)b * NL * NK;
    const bool isG = (g >= 16) && (g < 24);

    // clamped row index for prefetch beyond ends (duplicate loads, results unused)
    auto rowt = [&](int sp) -> int {
        int t = d ? (NL - 1 - sp) : sp;
        t = t < 0 ? 0 : t;
        t = t > NL - 1 ? NL - 1 : t;
        return t;
    };
    auto ld = [&](int sp, float* dst, float2& a) {
        const int t = rowt(sp);
        load16(srcb + (size_t)t * NK, dst);
        if constexpr (NORM) a = *(const float2*)(ansh + 2 * t);
    };
    auto step = [&](int s, const float* xr, float2 a) {
        const int t = d ? (NL - 1 - s) : s;
        float acc = 0.f;
        #pragma unroll
        for (int k = 0; k < 16; k++) acc += xr[k] * wih[k];
        if constexpr (NORM) acc = a.x * acc + a.y * Sg;
        #pragma unroll
        for (int k = 0; k < 8; k++) acc += whh[k] * __shfl(h, base + k, 64);
        float val = gate_act(acc, isG);
        float fv = __shfl(val, lane + 8, 64);
        float gv = __shfl(val, lane + 16, 64);
        float ov = __shfl(val, lane + 24, 64);
        float cn = fv * c + val * gv;      // valid for g<8 (val = sigmoid(i))
        float hn = ov * tanh_safe(cn);
        if (g < 8) { c = cn; h = hn; }
        if constexpr (WRITE_O) {
            if (g < 8) oout[((size_t)b * NL + t) * NK + (d << 3) + j] = hn;
        }
        if constexpr (WRITE_LAST) {
            if (s == 0 && d == 1 && g < 8) oblast[b * 8 + j] = hn;
        }
    };

    float B0[16], B1[16], B2[16], B3[16];
    float2 A0{0,0}, A1{0,0}, A2{0,0}, A3{0,0};
    ld(0, B0, A0); ld(1, B1, A1); ld(2, B2, A2);

    int s = 0;
    for (; s + 4 <= NL; s += 4) {
        ld(s + 3, B3, A3); step(s + 0, B0, A0);
        ld(s + 4, B0, A0); step(s + 1, B1, A1);
        ld(s + 5, B1, A1); step(s + 2, B2, A2);
        ld(s + 6, B2, A2); step(s + 3, B3, A3);
    }
    if (s     < NL) step(s,     B0, A0);
    if (s + 1 < NL) step(s + 1, B1, A1);
    if (s + 2 < NL) step(s + 2, B2, A2);

    if (g < 8) {
        float* hs = st + (d ? (size_t)2 * NB * 8 : 0);
        hs[b * 8 + j] = h;
        hs[(size_t)NB * 8 + b * 8 + j] = c;
    }
}

// ---------- K4: 96-step decode recurrence (cells only), store raw o to z ----------
__global__ __launch_bounds__(256) void k_dec(
    const float* __restrict__ Wf0, const float* __restrict__ Uf0,
    const float* __restrict__ Wb0, const float* __restrict__ Ub0,
    const float* __restrict__ Wf1, const float* __restrict__ Uf1,
    const float* __restrict__ Wb1, const float* __restrict__ Ub1,
    const float* __restrict__ st0, const float* __restrict__ st1,
    const float* __restrict__ oblast, const float* __restrict__ p,
    const float* __restrict__ ansh,
    const float* __restrict__ gln, const float* __restrict__ bln,
    float* __restrict__ z)
{
    const int tid = threadIdx.x, lane = tid & 63;
    const int b = blockIdx.x * 4 + (tid >> 6);
    const int d = lane >> 5, g = lane & 31, j = g & 7, base = d << 5;
    const float* Wih0 = d ? Wb0 : Wf0; const float* Whh0 = d ? Ub0 : Uf0;
    const float* Wih1 = d ? Wb1 : Wf1; const float* Whh1 = d ? Ub1 : Uf1;
    float wih0[16], whh0[8], wih1[16], whh1[8];
    #pragma unroll
    for (int k = 0; k < 16; k++) { wih0[k] = Wih0[g * 16 + k]; wih1[k] = Wih1[g * 16 + k]; }
    #pragma unroll
    for (int k = 0; k < 8; k++)  { whh0[k] = Whh0[g * 8 + k]; whh1[k] = Whh1[g * 8 + k]; }

    float h0 = 0.f, c0 = 0.f, h1 = 0.f, c1 = 0.f;
    if (g < 8) {
        const float* s0 = st0 + (d ? (size_t)2 * NB * 8 : 0);
        h0 = s0[b * 8 + j]; c0 = s0[(size_t)NB * 8 + b * 8 + j];
        const float* s1 = st1 + (d ? (size_t)2 * NB * 8 : 0);
        h1 = s1[b * 8 + j]; c1 = s1[(size_t)NB * 8 + b * 8 + j];
    }

    // fb = LN(concat(hf1_final, ob1_last)) * g_ln + b_ln + xe[:,L-1,:]
    float fb[16];
    {
        float ol[16];
        #pragma unroll
        for (int k = 0; k < 8; k++) ol[k] = st1[b * 8 + k];          // hF1 final == of1[:,L-1]
        #pragma unroll
        for (int k = 0; k < 8; k++) ol[8 + k] = oblast[b * 8 + k];   // ob1[:,L-1]
        float mn = 0.f;
        #pragma unroll
        for (int k = 0; k < 16; k++) mn += ol[k];
        mn *= (1.0f / 16.0f);
        float vv = 0.f;
        #pragma unroll
        for (int k = 0; k < 16; k++) { float dq = ol[k] - mn; vv += dq * dq; }
        vv *= (1.0f / 16.0f);
        float rr = rsqrtf(vv + 1e-5f);
        float aL = ansh[2 * (NL - 1)], sL = ansh[2 * (NL - 1) + 1];
        const float* prow = p + ((size_t)b * NL + (NL - 1)) * NK;
        #pragma unroll
        for (int k = 0; k < 16; k++)
            fb[k] = (ol[k] - mn) * rr * gln[k] + bln[k] + (prow[k] * aL + sL);
    }

    const bool isG = (g >= 16) && (g < 24);
    for (int t = 0; t < NT; t++) {
        // layer-0 cell
        float acc = 0.f;
        #pragma unroll
        for (int k = 0; k < 16; k++) acc += fb[k] * wih0[k];
        #pragma unroll
        for (int k = 0; k < 8; k++) acc += whh0[k] * __shfl(h0, base + k, 64);
        float val = gate_act(acc, isG);
        float fv = __shfl(val, lane + 8, 64);
        float gv = __shfl(val, lane + 16, 64);
        float ov = __shfl(val, lane + 24, 64);
        float cn = fv * c0 + val * gv;
        float hn = ov * tanh_safe(cn);
        if (g < 8) { c0 = cn; h0 = hn; }
        // m0 = concat(hf0, hb0) broadcast to all lanes
        float m0[16];
        #pragma unroll
        for (int k = 0; k < 16; k++) m0[k] = __shfl(h0, k < 8 ? k : 24 + k, 64);
        // layer-1 cell
        acc = 0.f;
        #pragma unroll
        for (int k = 0; k < 16; k++) acc += m0[k] * wih1[k];
        #pragma unroll
        for (int k = 0; k < 8; k++) acc += whh1[k] * __shfl(h1, base + k, 64);
        val = gate_act(acc, isG);
        fv = __shfl(val, lane + 8, 64);
        gv = __shfl(val, lane + 16, 64);
        ov = __shfl(val, lane + 24, 64);
        cn = fv * c1 + val * gv;
        hn = ov * tanh_safe(cn);
        if (g < 8) { c1 = cn; h1 = hn; }
        if (g < 8) z[((size_t)b * NT + t) * NK + (d << 3) + j] = hn;
        // new fb = raw o = concat(hf1, hb1)
        #pragma unroll
        for (int k = 0; k < 16; k++) fb[k] = __shfl(h1, k < 8 ? k : 24 + k, 64);
    }
}

// ---------- K5: decoder MLP over all (b,t) rows ----------
__global__ __launch_bounds__(256) void k_head(
    const float* __restrict__ z, const float* __restrict__ gln, const float* __restrict__ bln,
    const float* __restrict__ W1, const float* __restrict__ b1,
    const float* __restrict__ W2, const float* __restrict__ b2,
    float* __restrict__ outp)
{
    __shared__ float w1s[512 * 16];
    __shared__ float b1s[512];
    __shared__ float w2s[512];
    const int tid = threadIdx.x;
    for (int i = tid; i < 512 * 16 / 4; i += 256)
        ((float4*)w1s)[i] = ((const float4*)W1)[i];
    for (int i = tid; i < 512; i += 256) { b1s[i] = b1[i]; w2s[i] = W2[i]; }
    __syncthreads();

    const size_t r = (size_t)blockIdx.x * 256 + tid;   // r = b*NT + t, matches out layout
    float zr[16];
    load16(z + r * 16, zr);
    float mn = 0.f;
    #pragma unroll
    for (int k = 0; k < 16; k++) mn += zr[k];
    mn *= (1.0f / 16.0f);
    float vv = 0.f;
    #pragma unroll
    for (int k = 0; k < 16; k++) { float dq = zr[k] - mn; vv += dq * dq; }
    vv *= (1.0f / 16.0f);
    float rr = rsqrtf(vv + 1e-5f);
    float zn[16];
    #pragma unroll
    for (int k = 0; k < 16; k++) zn[k] = (zr[k] - mn) * rr * gln[k] + bln[k];

    float y = b2[0];
    #pragma unroll 2
    for (int i = 0; i < 512; i++) {
        float acc = b1s[i];
        #pragma unroll
        for (int k = 0; k < 16; k++) acc += zn[k] * w1s[i * 16 + k];
        y += gelu_exact(acc) * w2s[i];
    }
    outp[r] = y;
}

// ---------- launcher ----------
extern "C" void kernel_launch(void* const* d_in, const int* in_sizes, int n_in,
                              void* d_out, int out_size, void* d_ws, size_t ws_size,
                              hipStream_t stream)
{
    const float* x    = (const float*)d_in[0];
    const float* pe   = (const float*)d_in[1];
    const float* Wseg = (const float*)d_in[2];
    const float* bseg = (const float*)d_in[3];
    const float* gbn  = (const float*)d_in[4];
    const float* bbn  = (const float*)d_in[5];
    const float* Wf0  = (const float*)d_in[6];
    const float* Uf0  = (const float*)d_in[7];
    const float* Wb0  = (const float*)d_in[8];
    const float* Ub0  = (const float*)d_in[9];
    const float* Wf1  = (const float*)d_in[10];
    const float* Uf1  = (const float*)d_in[11];
    const float* Wb1  = (const float*)d_in[12];
    const float* Ub1  = (const float*)d_in[13];
    const float* gln  = (const float*)d_in[14];
    const float* bln  = (const float*)d_in[15];
    const float* W1   = (const float*)d_in[16];
    const float* b1   = (const float*)d_in[17];
    const float* W2   = (const float*)d_in[18];
    const float* b2   = (const float*)d_in[19];

    char* ws = (char*)d_ws;
    size_t off = 0;
    auto take = [&](size_t bytes) -> char* {
        char* r = ws + off;
        off = (off + bytes + 255) & ~(size_t)255;
        return r;
    };
    float* p    = (float*)take((size_t)NB * NL * NK * 4);   // 65.1 MB
    float* o0   = (float*)take((size_t)NB * NL * NK * 4);   // 65.1 MB
    float* z    = (float*)take((size_t)NB * NT * NK * 4);   // 12.6 MB
    float* bn   = (float*)take((size_t)NREP * 1024 * 4);    // 32 replicas of sums|sumsq
    float* ansh = (float*)take(1024 * 4);                   // interleaved (a,sh) pairs
    float* st0  = (float*)take((size_t)4 * NB * 8 * 4);     // hF|cF|hB|cB layer0
    float* st1  = (float*)take((size_t)4 * NB * 8 * 4);     // layer1
    float* obl  = (float*)take((size_t)NB * 8 * 4);         // ob1[:,L-1]

    hipMemsetAsync(bn, 0, (size_t)NREP * 1024 * 4, stream);
    k_seg<<<NB, 256, 0, stream>>>(x, pe, Wseg, bseg, p, bn);
    k_bnfin<<<2, 256, 0, stream>>>(bn, gbn, bbn, ansh);
    k_lstm<1, 1, 0><<<NB / 4, 256, 0, stream>>>(p, ansh, Wf0, Uf0, Wb0, Ub0, o0, st0, nullptr);
    k_lstm<0, 0, 1><<<NB / 4, 256, 0, stream>>>(o0, nullptr, Wf1, Uf1, Wb1, Ub1, nullptr, st1, obl);
    k_dec<<<NB / 4, 256, 0, stream>>>(Wf0, Uf0, Wb0, Ub0, Wf1, Uf1, Wb1, Ub1,
                                      st0, st1, obl, p, ansh, gln, bln, z);
    k_head<<<(NB * NT) / 256, 256, 0, stream>>>(z, gln, bln, W1, b1, W2, b2, (float*)d_out);
}